// Round 2
// 288.828 us; speedup vs baseline: 1.0250x; 1.0250x over previous
//
#include <hip/hip_runtime.h>
#include <math.h>

#define NN 4096
#define KK 32
#define KOb 32
#define BB 2
#define NSLOT 64   // Hbins partial slots (bounds global atomic contention)

constexpr float EPS = 1e-6f;

typedef float nfloat4 __attribute__((ext_vector_type(4)));  // native vec for NT builtins

// ---- workspace layout (in float elements) ----
#define WS_VALS   0                          // B*N*K floats
#define WS_IDX    (WS_VALS + BB*NN*KK)       // B*N*K ints
#define WS_HBP    (WS_IDX + BB*NN*KK)        // B*NSLOT*KO partials (memset 0)
#define WS_A1     (WS_HBP + BB*NSLOT*KOb)    // B*N*K
#define WS_M      (WS_A1 + BB*NN*KK)         // B*N
#define WS_CHI    (WS_M + BB*NN)             // B*N*K
#define WS_A2     (WS_CHI + BB*NN*KK)        // B*N*K
#define WS_SEV    (WS_A2 + BB*NN*KK)         // B*N
#define WS_TEV    (WS_SEV + BB*NN)           // B*N (zeroed in k_row2d)
#define WS_Q      (WS_TEV + BB*NN)           // B*N

// ---- output layout (float elements) ----
#define OUT_A2   0
#define OUT_U    ((size_t)BB*NN*NN)
#define OUT_PSRC (OUT_U + BB*NN)
#define OUT_PTGT (OUT_PSRC + BB*NN)
#define OUT_MAP  (OUT_PTGT + BB*NN)

__device__ __forceinline__ unsigned int fkey(float x) {
    unsigned int u = __float_as_uint(x);
    return u ^ ((unsigned int)((int)u >> 31) | 0x80000000u);
}
__device__ __forceinline__ float key2f(unsigned int k) {
    unsigned int u = (k & 0x80000000u) ? (k ^ 0x80000000u) : ~k;
    return __uint_as_float(u);
}

// =====================================================================
// K1: per-row top-32, ONE 256-thread BLOCK per row. 16 keys/lane in
// registers (nontemporal: A0 is read-once), block threshold search,
// prefix compaction <=64 cands, wave0 rank-select, fused Hbins.
// =====================================================================
__global__ __launch_bounds__(256) void k_topk(const float* __restrict__ A0,
                                              const float* __restrict__ bins,
                                              float* __restrict__ ws) {
    __shared__ float sbins[2 * KOb];
    __shared__ int   scnt[4];
    __shared__ int   swtot[4];
    __shared__ unsigned long long cand[64];
    __shared__ float selv[KK], seldx[KK], seldy[KK];
    __shared__ float shb[KOb];

    const int t = threadIdx.x;
    const int wv = t >> 6, lane = t & 63;
    const int R = blockIdx.x;
    const int b = R >> 12;
    const int r = R & (NN - 1);

    if (t < 2 * KOb) sbins[t] = bins[t];
    if (t < KOb) shb[t] = 0.f;

    // coalesced: thread t reads float4 #(i*256+t); elem of key[4i+c] = i*1024 + t*4 + c
    const nfloat4* row4 = (const nfloat4*)(A0 + (size_t)R * NN);
    unsigned int key[16];
    #pragma unroll
    for (int i = 0; i < 4; ++i) {
        const nfloat4 f = __builtin_nontemporal_load(row4 + i * 256 + t);
        key[4 * i + 0] = fkey(f.x);
        key[4 * i + 1] = fkey(f.y);
        key[4 * i + 2] = fkey(f.z);
        key[4 * i + 3] = fkey(f.w);
    }

    // ---- block-uniform threshold search: 32 <= count(key > lo) <= 64 ----
    unsigned int lo = 0u, hi = 0xFFFFFFFFu;
    int cnt = NN, it = 0;
    while (cnt > 64) {
        unsigned int mid;
        if (it == 0)      mid = 0xBF7E0000u;   // fkey(0.9921875) ~ E[cnt]=32
        else if (it == 1) mid = 0xBF7C4000u;   // fkey(0.98535)  ~ E[cnt]=60
        else              mid = lo + ((hi - lo) >> 1);
        if (mid <= lo || mid >= hi) mid = lo + ((hi - lo) >> 1);
        if (mid == lo) break;
        int cl = 0;
        #pragma unroll
        for (int j = 0; j < 16; ++j) cl += (key[j] > mid) ? 1 : 0;
        int c = cl;
        #pragma unroll
        for (int m = 32; m >= 1; m >>= 1) c += __shfl_xor(c, m);
        if (lane == 0) scnt[wv] = c;
        __syncthreads();
        const int ctot = scnt[0] + scnt[1] + scnt[2] + scnt[3];
        __syncthreads();
        if (ctot >= KK) { lo = mid; cnt = ctot; } else hi = mid;
        if (++it > 48) break;
    }

    // ---- block prefix compaction of candidates {key > lo} ----
    int cl = 0;
    #pragma unroll
    for (int j = 0; j < 16; ++j) cl += (key[j] > lo) ? 1 : 0;
    int inc = cl;
    #pragma unroll
    for (int m = 1; m < 64; m <<= 1) {
        const int o = __shfl_up(inc, m);
        if (lane >= m) inc += o;
    }
    if (lane == 63) swtot[wv] = inc;
    __syncthreads();
    int off = inc - cl;                        // exclusive within wave
    #pragma unroll
    for (int w = 0; w < 4; ++w) if (w < wv) off += swtot[w];
    const int nc0 = swtot[0] + swtot[1] + swtot[2] + swtot[3];
    const int ncand = (nc0 < 64) ? nc0 : 64;

    int slot = off;
    #pragma unroll
    for (int j = 0; j < 16; ++j) {
        if (key[j] > lo && slot < 64) {
            const unsigned int gidx = (unsigned int)((j >> 2) * 1024 + t * 4 + (j & 3));
            cand[slot] = ((unsigned long long)key[j] << 32)
                       | (unsigned long long)(4095u - gidx);
            ++slot;
        }
    }
    __syncthreads();

    // ---- wave 0: rank selection + emit; packed u64 gives exact tie-break ----
    if (t < 64) {
        const unsigned long long cd = (t < ncand) ? cand[t] : 0ull;
        int rank = 0;
        #pragma unroll
        for (int i = 0; i < 64; ++i) {
            const unsigned long long o = __shfl(cd, i);
            rank += (o > cd) ? 1 : 0;
        }
        if (t < ncand && rank < KK) {
            const float val = key2f((unsigned int)(cd >> 32));
            const int gidx = 4095 - (int)(cd & 0xFFFull);
            ws[WS_VALS + (size_t)R * KK + rank] = val;
            ((int*)(ws + WS_IDX))[(size_t)R * KK + rank] = gidx;
            selv[rank]  = val;
            seldx[rank] = (float)((gidx & 63) - (r & 63));
            seldy[rank] = (float)((gidx >> 6) - (r >> 6));
        }
    }
    __syncthreads();

    // ---- fused Hbins: 32 edges x 32 bins = 1024 tasks over 256 threads ----
    const int e = t >> 3;                       // edge 0..31
    const float v = selv[e], dx0 = seldx[e], dy0 = seldy[e];
    #pragma unroll
    for (int jj = 0; jj < 4; ++jj) {
        const int o = (lane & 7) * 4 + jj;      // bin, constant across xor-8/16/32 group
        const float dx = dx0 - sbins[2 * o], dy = dy0 - sbins[2 * o + 1];
        float contrib = v * __expf(-(dx * dx + dy * dy) * (1.0f / 4.5f));
        contrib += __shfl_xor(contrib, 8);
        contrib += __shfl_xor(contrib, 16);
        contrib += __shfl_xor(contrib, 32);
        if ((lane >> 3) == 0) atomicAdd(&shb[o], contrib);
    }
    __syncthreads();
    if (t < KOb)
        atomicAdd(ws + WS_HBP + b * (NSLOT * KOb) + (R & (NSLOT - 1)) * KOb + t,
                  shb[t]);
}

// =====================================================================
// K2: fused Hbins-reduce + Wsoft/Wmean (redundant per block, L2-hot)
// + per-row: R_edges -> A1 -> entropy -> U, m; also chi.
// 2 rows per wave (all 64 lanes active; shfl_xor masks <=16 stay
// within each 32-lane half) + packed float4 bin table (1 LDS read/iter).
// =====================================================================
__global__ __launch_bounds__(256) void k_row1(const float* __restrict__ bins,
                                              float* __restrict__ ws,
                                              float* __restrict__ out_u) {
    __shared__ float  sbins[2 * KOb];
    __shared__ float  sHB[BB * KOb];
    __shared__ float  swsoft[BB * KOb];
    __shared__ float4 stbl[BB * KOb];   // {bin_x, bin_y, wsoft[b][o], wmean[o]}
    const int t = threadIdx.x;
    if (t < 2 * KOb) sbins[t] = bins[t];
    if (t >= 64 && t < 64 + BB * KOb) sHB[t - 64] = 0.f;
    __syncthreads();

    #pragma unroll
    for (int rep = 0; rep < 2; ++rep) {
        const int task = t + 256 * rep;
        const int bo = task & 63;
        const int sg = task >> 6;
        float ps = 0.f;
        #pragma unroll
        for (int s = 0; s < 8; ++s)
            ps += ws[WS_HBP + (bo >> 5) * (NSLOT * KOb) + (sg * 8 + s) * KOb + (bo & 31)];
        atomicAdd(&sHB[bo], ps);
    }
    __syncthreads();
    if (t < BB * KOb) {
        const float h = 8.0f * sHB[t];
        float mx = h;
        #pragma unroll
        for (int m = 16; m >= 1; m >>= 1) mx = fmaxf(mx, __shfl_xor(mx, m));
        const float e = __expf(h - mx);
        float s = e;
        #pragma unroll
        for (int m = 16; m >= 1; m >>= 1) s += __shfl_xor(s, m);
        swsoft[t] = e / s;
    }
    if (t < BB * KOb) {                 // same wave as above: no barrier needed
        const int o = t & 31;
        const float wm = 0.5f * (swsoft[o] + swsoft[KOb + o]);
        stbl[t] = make_float4(sbins[2 * o], sbins[2 * o + 1], swsoft[t], wm);
    }
    __syncthreads();

    const int wv = t >> 6, lane = t & 63;
    const int half = lane >> 5, k = lane & 31;
    const int R = blockIdx.x * 8 + wv * 2 + half;
    const int b = R >> 12;
    const int r = R & (NN - 1);

    const float val = ws[WS_VALS + (size_t)R * KK + k];
    const int c = ((int*)(ws + WS_IDX))[(size_t)R * KK + k];
    const float dx0 = (float)((c & 63) - (r & 63));
    const float dy0 = (float)((c >> 6) - (r >> 6));
    float racc = 0.f, cacc = 0.f;
    const float4* tb = stbl + (b << 5);
    #pragma unroll
    for (int o = 0; o < KOb; ++o) {
        const float4 cb = tb[o];
        const float dx = dx0 - cb.x, dy = dy0 - cb.y;
        const float kap = __expf(-(dx * dx + dy * dy) * (1.0f / 4.5f));
        racc += cb.z * kap;
        cacc += cb.w * kap;
    }
    const float Redge = 0.001f + racc;
    const float chi = cacc;

    const float tilde = val * Redge;
    float s = tilde;
    #pragma unroll
    for (int m = 16; m >= 1; m >>= 1) s += __shfl_xor(s, m);
    const float a1 = tilde / (s + EPS);

    const float z = 10.f * a1;
    float mz = z;
    #pragma unroll
    for (int m = 16; m >= 1; m >>= 1) mz = fmaxf(mz, __shfl_xor(mz, m));
    const float e = __expf(z - mz);
    float se = e;
    #pragma unroll
    for (int m = 16; m >= 1; m >>= 1) se += __shfl_xor(se, m);
    const float p = e / se;
    const float ent_t = -p * __logf(p + EPS);
    float ent = ent_t;
    #pragma unroll
    for (int m = 16; m >= 1; m >>= 1) ent += __shfl_xor(ent, m);
    const float U = 1.f / (1.f + __expf(ent));

    ws[WS_A1  + (size_t)R * KK + k] = a1;
    ws[WS_CHI + (size_t)R * KK + k] = chi;
    if (k == 0) { out_u[R] = U; ws[WS_M + R] = 1.f - U; }
}

// =====================================================================
// K3: fused row2 + dense write. One block per row: wave 0 does the
// math (hatA -> A2_edges -> dv, q), whole block streams the dense row
// (nontemporal: written once, never re-read by us).
// Also zero-fills WS_TEV (blocks 0..31).
// =====================================================================
__global__ __launch_bounds__(256) void k_row2d(float* __restrict__ ws,
                                               float* __restrict__ outA2) {
    __shared__ float srow[NN];
    __shared__ float sdv[KK];
    __shared__ int   sidx[KK];
    const int R = blockIdx.x;
    const int b = R >> 12;
    const int t = threadIdx.x;

    const int gid = blockIdx.x * 256 + t;
    if (gid < BB * NN) ws[WS_TEV + gid] = 0.f;

    nfloat4* s4 = (nfloat4*)srow;
    const nfloat4 z4 = {0.f, 0.f, 0.f, 0.f};
    #pragma unroll
    for (int i = 0; i < 4; ++i) s4[t + 256 * i] = z4;

    if (t < 64) {
        const int lane = t;
        const bool act = lane < 32;
        const int k = lane;
        const float mi = ws[WS_M + R];
        float a1 = 0.f; int c = 0; float mj = 0.f;
        if (act) {
            a1 = ws[WS_A1 + (size_t)R * KK + k];
            c = ((int*)(ws + WS_IDX))[(size_t)R * KK + k];
            mj = ws[WS_M + b * NN + c];
        }
        const float hat = act ? mi * a1 * mj : 0.f;
        float S = hat;
        #pragma unroll
        for (int m = 16; m >= 1; m >>= 1) S += __shfl_xor(S, m);
        const float a2e = hat / (S + EPS);
        float S2 = a2e;
        #pragma unroll
        for (int m = 16; m >= 1; m >>= 1) S2 += __shfl_xor(S2, m);
        const float dv = a2e / (S2 + EPS);

        const float z = act ? 8.f * a2e : -1e30f;
        float mz = z;
        #pragma unroll
        for (int m = 16; m >= 1; m >>= 1) mz = fmaxf(mz, __shfl_xor(mz, m));
        const float e = act ? __expf(z - mz) : 0.f;
        float se = e;
        #pragma unroll
        for (int m = 16; m >= 1; m >>= 1) se += __shfl_xor(se, m);
        const float wl = e / se;
        const float chi = act ? ws[WS_CHI + (size_t)R * KK + k] : 0.f;
        float q = act ? wl * chi : 0.f;
        #pragma unroll
        for (int m = 16; m >= 1; m >>= 1) q += __shfl_xor(q, m);
        if (lane == 0) ws[WS_Q + R] = q;

        if (act) {
            ws[WS_A2 + (size_t)R * KK + k] = dv;
            sdv[k] = dv;
            sidx[k] = c;
        }
    }
    __syncthreads();
    if (t < KK) srow[sidx[t]] = sdv[t];
    __syncthreads();
    nfloat4* o4 = (nfloat4*)(outA2 + (size_t)R * NN);
    #pragma unroll
    for (int i = 0; i < 4; ++i)
        __builtin_nontemporal_store(s4[t + 256 * i], o4 + t + 256 * i);
}

// =====================================================================
// K4: directional evidence — reverse value found by searching row c's
// 32 indices in the L2-resident edge arrays (2 MB).
// 2 rows per wave — all 64 lanes active.
// =====================================================================
__global__ __launch_bounds__(256) void k_dir(float* __restrict__ ws) {
    const int t = threadIdx.x;
    const int wv = t >> 6, lane = t & 63;
    const int half = lane >> 5, k = lane & 31;
    const int R = blockIdx.x * 8 + wv * 2 + half;
    const int b = R >> 12;
    const int r = R & (NN - 1);

    const float a = ws[WS_A2 + (size_t)R * KK + k];
    const int c = ((int*)(ws + WS_IDX))[(size_t)R * KK + k];
    float pdir = 0.f;
    if (c != r) {
        const int4* irow = (const int4*)((const int*)(ws + WS_IDX)
                                         + (size_t)(b * NN + c) * KK);
        int p = -1;
        #pragma unroll
        for (int q = 0; q < 8; ++q) {
            const int4 i4 = irow[q];
            if (i4.x == r) p = q * 4 + 0;
            if (i4.y == r) p = q * 4 + 1;
            if (i4.z == r) p = q * 4 + 2;
            if (i4.w == r) p = q * 4 + 3;
        }
        const float arev = (p >= 0) ? ws[WS_A2 + (size_t)(b * NN + c) * KK + p] : 0.f;
        const float ef = __expf(8.f * a), er = __expf(8.f * arev);
        pdir = ef / (ef + er + EPS);
    }
    float s = a * pdir;
    #pragma unroll
    for (int m = 16; m >= 1; m >>= 1) s += __shfl_xor(s, m);
    if (k == 0) ws[WS_SEV + R] = s;
    atomicAdd(ws + WS_TEV + b * NN + c, a * (1.f - pdir));
}

// =====================================================================
// K5: fused pi_src/pi_tgt + 5x5 gaussian smoothing + sigmoid.
// =====================================================================
__global__ void k_tail(const float* __restrict__ ws, const float* __restrict__ kern,
                       float* __restrict__ out_psrc, float* __restrict__ out_ptgt,
                       float* __restrict__ out_map) {
    const int i = blockIdx.x * 256 + threadIdx.x;
    const float s = ws[WS_SEV + i], tv = ws[WS_TEV + i];
    const float ps = s / (s + tv + EPS);
    out_psrc[i] = ps;
    out_ptgt[i] = 1.f - ps;

    const int b = i >> 12;
    const int pix = i & 4095;
    const int y = pix >> 6, x = pix & 63;
    float acc = 0.f;
    #pragma unroll
    for (int ky = 0; ky < 5; ++ky) {
        const int yy = y + ky - 2;
        if (yy < 0 || yy >= 64) continue;
        #pragma unroll
        for (int kx = 0; kx < 5; ++kx) {
            const int xx = x + kx - 2;
            if (xx < 0 || xx >= 64) continue;
            acc += ws[WS_Q + b * 4096 + yy * 64 + xx] * kern[ky * 5 + kx];
        }
    }
    out_map[i] = 1.f / (1.f + __expf(-acc));
}

extern "C" void kernel_launch(void* const* d_in, const int* in_sizes, int n_in,
                              void* d_out, int out_size, void* d_ws, size_t ws_size,
                              hipStream_t stream) {
    const float* A0   = (const float*)d_in[1];
    const float* bins = (const float*)d_in[3];
    const float* kern = (const float*)d_in[4];
    float* out = (float*)d_out;
    float* ws  = (float*)d_ws;

    (void)hipMemsetAsync(ws + WS_HBP, 0, BB * NSLOT * KOb * sizeof(float), stream);

    k_topk <<<BB * NN,       256, 0, stream>>>(A0, bins, ws);
    k_row1 <<<BB * NN / 8,   256, 0, stream>>>(bins, ws, out + OUT_U);
    k_row2d<<<BB * NN,       256, 0, stream>>>(ws, out);
    k_dir  <<<BB * NN / 8,   256, 0, stream>>>(ws);
    k_tail <<<BB * NN / 256, 256, 0, stream>>>(ws, kern,
                                               out + OUT_PSRC, out + OUT_PTGT,
                                               out + OUT_MAP);
}